// Round 1
// baseline (429.935 us; speedup 1.0000x reference)
//
#include <hip/hip_runtime.h>
#include <math.h>

namespace {

constexpr int DD = 128;
constexpr int DM = 127;
constexpr int D3 = DD * DD * DD;

struct Consts {
  float kn, ps, eta, dtpm, grav;
  float lo_hi;   // 1.5*PS
  float hi_th;   // D*CELL - 0.5*PS - CELL
  float dcell;   // D*CELL
  float cell;    // CELL
  float hps;     // 0.5*PS
};

__device__ inline float bforce(float p, float v, float mkv, const Consts& c) {
  float lo = ((p > c.ps) && (p < c.lo_hi)) ? mkv : 0.0f;
  float hi = (p > c.hi_th) ? mkv : 0.0f;
  float t = ((p - c.dcell) + c.cell) + c.hps;   // mirrors ref op order
  return c.kn * lo * (c.lo_hi - p) - c.kn * hi * t - c.eta * v * lo - c.eta * v * hi;
}

// Accumulate contact forces over offsets |o| <= R for both particle layers.
template <int R>
__device__ void collide(int x, int y, int z,
                        const float* __restrict__ xg, const float* __restrict__ yg,
                        const float* __restrict__ zg,
                        const float* __restrict__ v0x, const float* __restrict__ v0y,
                        const float* __restrict__ v0z,
                        const float* __restrict__ v1x, const float* __restrict__ v1y,
                        const float* __restrict__ v1z,
                        float xn, float yn, float zn,
                        float vxn, float vyn, float vzn,
                        float& fx, float& fy, float& fz, const Consts& c) {
  int xw[2 * R + 1];
#pragma unroll
  for (int ox = -R; ox <= R; ++ox) xw[ox + R] = (x + ox) & DM;

  for (int oz = -R; oz <= R; ++oz) {
    const int zr = (z + oz) & DM;
    for (int oy = -R; oy <= R; ++oy) {
      const int yr = (y + oy) & DM;
      const int rb = (zr * DD + yr) * DD;
#pragma unroll
      for (int m = 0; m < 2; ++m) {
        const float* __restrict__ PX = xg + m * D3 + rb;
        const float* __restrict__ PY = yg + m * D3 + rb;
        const float* __restrict__ PZ = zg + m * D3 + rb;
        const float* __restrict__ VX = (m == 0 ? v0x : v1x) + rb;
        const float* __restrict__ VY = (m == 0 ? v0y : v1y) + rb;
        const float* __restrict__ VZ = (m == 0 ? v0z : v1z) + rb;
#pragma unroll
        for (int ox = -R; ox <= R; ++ox) {
          const int xi = xw[ox + R];
          float dx = xn - PX[xi];
          float dy = yn - PY[xi];
          float dz = zn - PZ[xi];
          float d2 = fmaf(dx, dx, fmaf(dy, dy, dz * dz));
          float d2c = fmaxf(d2, 1e-12f);
          float r = __builtin_amdgcn_rsqf(d2c);   // ~1 ulp
          float dist = d2c * r;                   // = sqrt(d2c)
          float inv = fminf(r, 1.0e4f);           // = 1/max(dist, 1e-4)
          float dvx = vxn - VX[xi];
          float dvy = vyn - VY[xi];
          float dvz = vzn - VZ[xi];
          float dvn = fmaf(dvx, dx, fmaf(dvy, dy, dvz * dz)) * inv;
          float coef = (dist < c.ps) ? (fmaf(c.kn, dist - c.ps, c.eta * dvn) * inv) : 0.0f;
          fx = fmaf(coef, dx, fx);
          fy = fmaf(coef, dy, fy);
          fz = fmaf(coef, dz, fz);
        }
      }
    }
  }
}

// Verify jitter bound: pos - corner in [-1e-5, CELL + 1e-5] for every cell/axis/layer.
// If it holds, offsets with any |axis offset| == 2 are provably force-free.
__global__ void __launch_bounds__(256)
checker(const float* __restrict__ xg, const float* __restrict__ yg,
        const float* __restrict__ zg, unsigned* flag, float cell) {
  int i = blockIdx.x * 256 + threadIdx.x;   // i in [0, 2*D3)
  int ix = i & DM;
  int iy = (i >> 7) & DM;
  int iz = (i >> 14) & DM;
  float jx = xg[i] - ix * cell;
  float jy = yg[i] - iy * cell;
  float jz = zg[i] - iz * cell;
  const float lo = -1e-5f, hi = cell + 1e-5f;
  bool bad = (jx < lo) | (jx > hi) | (jy < lo) | (jy > hi) | (jz < lo) | (jz > hi);
  if (bad) atomicOr(flag, 1u);
}

__global__ void __launch_bounds__(256)
dem_pass(int n,
         const float* __restrict__ xg, const float* __restrict__ yg,
         const float* __restrict__ zg,
         const float* __restrict__ v0x, const float* __restrict__ v0y,
         const float* __restrict__ v0z,
         const float* __restrict__ v1x, const float* __restrict__ v1y,
         const float* __restrict__ v1z,
         const float* __restrict__ vnx, const float* __restrict__ vny,
         const float* __restrict__ vnz,
         const float* __restrict__ maskn,
         float* __restrict__ outx, float* __restrict__ outy, float* __restrict__ outz,
         const unsigned* __restrict__ flag, Consts cc) {
  const int x = threadIdx.x;
  const int y = blockIdx.y * 2 + threadIdx.y;
  const int z = blockIdx.z;
  const int idx = (z * DD + y) * DD + x;
  const int nn = n * D3;

  const float xn = xg[nn + idx];
  const float yn = yg[nn + idx];
  const float zn = zg[nn + idx];
  const float vxn = vnx[idx];
  const float vyn = vny[idx];
  const float vzn = vnz[idx];

  float fx = 0.0f, fy = 0.0f, fz = 0.0f;
  if (*flag == 0u) {
    collide<1>(x, y, z, xg, yg, zg, v0x, v0y, v0z, v1x, v1y, v1z,
               xn, yn, zn, vxn, vyn, vzn, fx, fy, fz, cc);
  } else {
    collide<2>(x, y, z, xg, yg, zg, v0x, v0y, v0z, v1x, v1y, v1z,
               xn, yn, zn, vxn, vyn, vzn, fx, fy, fz, cc);
  }

  const float mkv = maskn[idx];
  const float fxb = bforce(xn, vxn, mkv, cc);
  const float fyb = bforce(yn, vyn, mkv, cc);
  const float fzb = bforce(zn, vzn, mkv, cc);
  const float s = cc.dtpm * mkv;
  outx[idx] = vxn + s * (fxb - fx);
  outy[idx] = vyn + s * (fyb - fy);
  outz[idx] = vzn + s * ((cc.grav - fz) + fzb);
}

}  // namespace

extern "C" void kernel_launch(void* const* d_in, const int* in_sizes, int n_in,
                              void* d_out, int out_size, void* d_ws, size_t ws_size,
                              hipStream_t stream) {
  const float* xg = (const float*)d_in[0];
  const float* yg = (const float*)d_in[1];
  const float* zg = (const float*)d_in[2];
  const float* vx = (const float*)d_in[3];
  const float* vy = (const float*)d_in[4];
  const float* vz = (const float*)d_in[5];
  const float* mk = (const float*)d_in[6];
  float* out = (float*)d_out;
  unsigned* flag = (unsigned*)d_ws;

  // Constants mirroring the Python reference, computed in double then cast.
  const double PSd = 0.1, CELLd = 0.1, KNd = 6.0e6;
  const double ALPHA = -log(0.5) / 3.141592653589793;
  const double GAMMA = ALPHA / sqrt(ALPHA * ALPHA + 1.0);
  const double PMd = 4.0 / 3.0 * 3.1415 * (0.1 * 0.1 * 0.1) * 2700.0;
  const double ETAd = 2.0 * GAMMA * sqrt(KNd * PMd);

  Consts cc;
  cc.kn = (float)KNd;
  cc.ps = (float)PSd;
  cc.eta = (float)ETAd;
  cc.dtpm = (float)(1e-4 / PMd);
  cc.grav = (float)(-9.8 * PMd);
  cc.lo_hi = (float)(1.5 * PSd);
  cc.hi_th = (float)(DD * CELLd - 0.5 * PSd - CELLd);
  cc.dcell = (float)(DD * CELLd);
  cc.cell = (float)CELLd;
  cc.hps = (float)(0.5 * PSd);

  hipMemsetAsync(d_ws, 0, sizeof(unsigned), stream);
  checker<<<(2 * D3) / 256, 256, 0, stream>>>(xg, yg, zg, flag, cc.cell);

  dim3 blk(128, 2, 1), grd(1, 64, 128);
  // Pass n=0: neighbor velocities = original inputs (both layers); own = input layer 0.
  dem_pass<<<grd, blk, 0, stream>>>(
      0, xg, yg, zg,
      vx, vy, vz,                       // m=0 source (input layer 0)
      vx + D3, vy + D3, vz + D3,        // m=1 source (input layer 1)
      vx, vy, vz,                       // own layer-0 velocities
      mk,
      out, out + 2 * D3, out + 4 * D3,  // out layer-0 slots of vx,vy,vz
      flag, cc);
  // Pass n=1: m=0 source is the UPDATED layer 0 (just written to out); own = input layer 1.
  dem_pass<<<grd, blk, 0, stream>>>(
      1, xg, yg, zg,
      out, out + 2 * D3, out + 4 * D3,  // m=0 source (updated layer 0)
      vx + D3, vy + D3, vz + D3,        // m=1 source (input layer 1)
      vx + D3, vy + D3, vz + D3,        // own layer-1 velocities
      mk + D3,
      out + D3, out + 3 * D3, out + 5 * D3,
      flag, cc);
}

// Round 2
// 316.265 us; speedup vs baseline: 1.3594x; 1.3594x over previous
//
#include <hip/hip_runtime.h>
#include <math.h>

namespace {

constexpr int DD = 128;
constexpr int DM = 127;
constexpr int D3 = DD * DD * DD;

struct Consts {
  float kn, ps, eta, dtpm, grav;
  float lo_hi;   // 1.5*PS
  float hi_th;   // D*CELL - 0.5*PS - CELL
  float dcell;   // D*CELL
  float cell;    // CELL
  float hps;     // 0.5*PS
};

__device__ inline float bforce(float p, float v, float mkv, const Consts& c) {
  float lo = ((p > c.ps) && (p < c.lo_hi)) ? mkv : 0.0f;
  float hi = (p > c.hi_th) ? mkv : 0.0f;
  float t = ((p - c.dcell) + c.cell) + c.hps;   // mirrors ref op order
  return c.kn * lo * (c.lo_hi - p) - c.kn * hi * t - c.eta * v * lo - c.eta * v * hi;
}

// Scalar fallback (R=2, full 125-offset correctness path; rarely taken).
template <int R>
__device__ void collide(int x, int y, int z,
                        const float* __restrict__ xg, const float* __restrict__ yg,
                        const float* __restrict__ zg,
                        const float* __restrict__ v0x, const float* __restrict__ v0y,
                        const float* __restrict__ v0z,
                        const float* __restrict__ v1x, const float* __restrict__ v1y,
                        const float* __restrict__ v1z,
                        float xn, float yn, float zn,
                        float vxn, float vyn, float vzn,
                        float& fx, float& fy, float& fz, const Consts& c) {
  int xw[2 * R + 1];
#pragma unroll
  for (int ox = -R; ox <= R; ++ox) xw[ox + R] = (x + ox) & DM;

  for (int oz = -R; oz <= R; ++oz) {
    const int zr = (z + oz) & DM;
    for (int oy = -R; oy <= R; ++oy) {
      const int yr = (y + oy) & DM;
      const int rb = (zr * DD + yr) * DD;
#pragma unroll
      for (int m = 0; m < 2; ++m) {
        const float* __restrict__ PX = xg + m * D3 + rb;
        const float* __restrict__ PY = yg + m * D3 + rb;
        const float* __restrict__ PZ = zg + m * D3 + rb;
        const float* __restrict__ VX = (m == 0 ? v0x : v1x) + rb;
        const float* __restrict__ VY = (m == 0 ? v0y : v1y) + rb;
        const float* __restrict__ VZ = (m == 0 ? v0z : v1z) + rb;
#pragma unroll
        for (int ox = -R; ox <= R; ++ox) {
          const int xi = xw[ox + R];
          float dx = xn - PX[xi];
          float dy = yn - PY[xi];
          float dz = zn - PZ[xi];
          float d2 = fmaf(dx, dx, fmaf(dy, dy, dz * dz));
          float d2c = fmaxf(d2, 1e-12f);
          float r = __builtin_amdgcn_rsqf(d2c);
          float dist = d2c * r;
          float inv = fminf(r, 1.0e4f);
          float dvx = vxn - VX[xi];
          float dvy = vyn - VY[xi];
          float dvz = vzn - VZ[xi];
          float dvn = fmaf(dvx, dx, fmaf(dvy, dy, dvz * dz)) * inv;
          float coef = (dist < c.ps) ? (fmaf(c.kn, dist - c.ps, c.eta * dvn) * inv) : 0.0f;
          fx = fmaf(coef, dx, fx);
          fy = fmaf(coef, dy, fy);
          fz = fmaf(coef, dz, fz);
        }
      }
    }
  }
}

__global__ void __launch_bounds__(256)
checker(const float* __restrict__ xg, const float* __restrict__ yg,
        const float* __restrict__ zg, unsigned* flag, float cell) {
  int i = blockIdx.x * 256 + threadIdx.x;   // i in [0, 2*D3)
  int ix = i & DM;
  int iy = (i >> 7) & DM;
  int iz = (i >> 14) & DM;
  float jx = xg[i] - ix * cell;
  float jy = yg[i] - iy * cell;
  float jz = zg[i] - iz * cell;
  const float lo = -1e-5f, hi = cell + 1e-5f;
  bool bad = (jx < lo) | (jx > hi) | (jy < lo) | (jy > hi) | (jz < lo) | (jz > hi);
  if (bad) atomicOr(flag, 1u);
}

// Vectorized pass: 4 x-cells per thread; neighbor rows loaded as float4 + 2 halo
// scalars shared by the 4 cells' 3 x-offsets; 4 independent VALU chains per thread.
__global__ void __launch_bounds__(256)
dem_pass(int n,
         const float* __restrict__ xg, const float* __restrict__ yg,
         const float* __restrict__ zg,
         const float* __restrict__ v0x, const float* __restrict__ v0y,
         const float* __restrict__ v0z,
         const float* __restrict__ v1x, const float* __restrict__ v1y,
         const float* __restrict__ v1z,
         const float* __restrict__ vnx, const float* __restrict__ vny,
         const float* __restrict__ vnz,
         const float* __restrict__ maskn,
         float* __restrict__ outx, float* __restrict__ outy, float* __restrict__ outz,
         const unsigned* __restrict__ flag, Consts cc) {
  const int tx = threadIdx.x;            // 0..31
  const int x0 = tx * 4;
  const int y = blockIdx.y * 8 + threadIdx.y;
  const int z = blockIdx.z;
  const int idx = (z * DD + y) * DD + x0;
  const int nn = n * D3;

  const float4 xc4 = *(const float4*)(xg + nn + idx);
  const float4 yc4 = *(const float4*)(yg + nn + idx);
  const float4 zc4 = *(const float4*)(zg + nn + idx);
  const float4 vx4 = *(const float4*)(vnx + idx);
  const float4 vy4 = *(const float4*)(vny + idx);
  const float4 vz4 = *(const float4*)(vnz + idx);
  const float4 mk4 = *(const float4*)(maskn + idx);

  float pxc[4] = {xc4.x, xc4.y, xc4.z, xc4.w};
  float pyc[4] = {yc4.x, yc4.y, yc4.z, yc4.w};
  float pzc[4] = {zc4.x, zc4.y, zc4.z, zc4.w};
  float vxc[4] = {vx4.x, vx4.y, vx4.z, vx4.w};
  float vyc[4] = {vy4.x, vy4.y, vy4.z, vy4.w};
  float vzc[4] = {vz4.x, vz4.y, vz4.z, vz4.w};
  float mkc[4] = {mk4.x, mk4.y, mk4.z, mk4.w};

  float fxA[4] = {0.f, 0.f, 0.f, 0.f};
  float fyA[4] = {0.f, 0.f, 0.f, 0.f};
  float fzA[4] = {0.f, 0.f, 0.f, 0.f};

  if (*flag == 0u) {
    const int xm1 = (x0 - 1) & DM;
    const int xp4 = (x0 + 4) & DM;
    for (int oz = -1; oz <= 1; ++oz) {
      const int zr = (z + oz) & DM;
      for (int oy = -1; oy <= 1; ++oy) {
        const int yr = (y + oy) & DM;
        const int rb = (zr * DD + yr) * DD;
#pragma unroll
        for (int m = 0; m < 2; ++m) {
          const float* __restrict__ PX = xg + m * D3 + rb;
          const float* __restrict__ PY = yg + m * D3 + rb;
          const float* __restrict__ PZ = zg + m * D3 + rb;
          const float* __restrict__ VX = (m == 0 ? v0x : v1x) + rb;
          const float* __restrict__ VY = (m == 0 ? v0y : v1y) + rb;
          const float* __restrict__ VZ = (m == 0 ? v0z : v1z) + rb;

          float wx[6], wy[6], wz[6], wvx[6], wvy[6], wvz[6];
          {
            float4 t;
            t = *(const float4*)(PX + x0);
            wx[0] = PX[xm1]; wx[1] = t.x; wx[2] = t.y; wx[3] = t.z; wx[4] = t.w; wx[5] = PX[xp4];
            t = *(const float4*)(PY + x0);
            wy[0] = PY[xm1]; wy[1] = t.x; wy[2] = t.y; wy[3] = t.z; wy[4] = t.w; wy[5] = PY[xp4];
            t = *(const float4*)(PZ + x0);
            wz[0] = PZ[xm1]; wz[1] = t.x; wz[2] = t.y; wz[3] = t.z; wz[4] = t.w; wz[5] = PZ[xp4];
            t = *(const float4*)(VX + x0);
            wvx[0] = VX[xm1]; wvx[1] = t.x; wvx[2] = t.y; wvx[3] = t.z; wvx[4] = t.w; wvx[5] = VX[xp4];
            t = *(const float4*)(VY + x0);
            wvy[0] = VY[xm1]; wvy[1] = t.x; wvy[2] = t.y; wvy[3] = t.z; wvy[4] = t.w; wvy[5] = VY[xp4];
            t = *(const float4*)(VZ + x0);
            wvz[0] = VZ[xm1]; wvz[1] = t.x; wvz[2] = t.y; wvz[3] = t.z; wvz[4] = t.w; wvz[5] = VZ[xp4];
          }

#pragma unroll
          for (int i = 0; i < 4; ++i) {
#pragma unroll
            for (int ox = 0; ox < 3; ++ox) {
              const int w = i + ox;
              float dx = pxc[i] - wx[w];
              float dy = pyc[i] - wy[w];
              float dz = pzc[i] - wz[w];
              float d2 = fmaf(dx, dx, fmaf(dy, dy, dz * dz));
              float d2c = fmaxf(d2, 1e-12f);
              float r = __builtin_amdgcn_rsqf(d2c);
              float dist = d2c * r;
              float inv = fminf(r, 1.0e4f);
              float dvx = vxc[i] - wvx[w];
              float dvy = vyc[i] - wvy[w];
              float dvz = vzc[i] - wvz[w];
              float dvn = fmaf(dvx, dx, fmaf(dvy, dy, dvz * dz)) * inv;
              float coef = (dist < cc.ps) ? (fmaf(cc.kn, dist - cc.ps, cc.eta * dvn) * inv) : 0.0f;
              fxA[i] = fmaf(coef, dx, fxA[i]);
              fyA[i] = fmaf(coef, dy, fyA[i]);
              fzA[i] = fmaf(coef, dz, fzA[i]);
            }
          }
        }
      }
    }
  } else {
#pragma unroll
    for (int i = 0; i < 4; ++i) {
      collide<2>(x0 + i, y, z, xg, yg, zg, v0x, v0y, v0z, v1x, v1y, v1z,
                 pxc[i], pyc[i], pzc[i], vxc[i], vyc[i], vzc[i],
                 fxA[i], fyA[i], fzA[i], cc);
    }
  }

  float4 ox4, oy4, oz4;
  float* po[3] = {&ox4.x, &oy4.x, &oz4.x};
  (void)po;
#pragma unroll
  for (int i = 0; i < 4; ++i) {
    const float fxb = bforce(pxc[i], vxc[i], mkc[i], cc);
    const float fyb = bforce(pyc[i], vyc[i], mkc[i], cc);
    const float fzb = bforce(pzc[i], vzc[i], mkc[i], cc);
    const float s = cc.dtpm * mkc[i];
    (&ox4.x)[i] = vxc[i] + s * (fxb - fxA[i]);
    (&oy4.x)[i] = vyc[i] + s * (fyb - fyA[i]);
    (&oz4.x)[i] = vzc[i] + s * ((cc.grav - fzA[i]) + fzb);
  }
  *(float4*)(outx + idx) = ox4;
  *(float4*)(outy + idx) = oy4;
  *(float4*)(outz + idx) = oz4;
}

}  // namespace

extern "C" void kernel_launch(void* const* d_in, const int* in_sizes, int n_in,
                              void* d_out, int out_size, void* d_ws, size_t ws_size,
                              hipStream_t stream) {
  const float* xg = (const float*)d_in[0];
  const float* yg = (const float*)d_in[1];
  const float* zg = (const float*)d_in[2];
  const float* vx = (const float*)d_in[3];
  const float* vy = (const float*)d_in[4];
  const float* vz = (const float*)d_in[5];
  const float* mk = (const float*)d_in[6];
  float* out = (float*)d_out;
  unsigned* flag = (unsigned*)d_ws;

  const double PSd = 0.1, CELLd = 0.1, KNd = 6.0e6;
  const double ALPHA = -log(0.5) / 3.141592653589793;
  const double GAMMA = ALPHA / sqrt(ALPHA * ALPHA + 1.0);
  const double PMd = 4.0 / 3.0 * 3.1415 * (0.1 * 0.1 * 0.1) * 2700.0;
  const double ETAd = 2.0 * GAMMA * sqrt(KNd * PMd);

  Consts cc;
  cc.kn = (float)KNd;
  cc.ps = (float)PSd;
  cc.eta = (float)ETAd;
  cc.dtpm = (float)(1e-4 / PMd);
  cc.grav = (float)(-9.8 * PMd);
  cc.lo_hi = (float)(1.5 * PSd);
  cc.hi_th = (float)(DD * CELLd - 0.5 * PSd - CELLd);
  cc.dcell = (float)(DD * CELLd);
  cc.cell = (float)CELLd;
  cc.hps = (float)(0.5 * PSd);

  hipMemsetAsync(d_ws, 0, sizeof(unsigned), stream);
  checker<<<(2 * D3) / 256, 256, 0, stream>>>(xg, yg, zg, flag, cc.cell);

  dim3 blk(32, 8, 1), grd(1, 16, 128);
  // Pass n=0: neighbor velocities = original inputs (both layers); own = input layer 0.
  dem_pass<<<grd, blk, 0, stream>>>(
      0, xg, yg, zg,
      vx, vy, vz,
      vx + D3, vy + D3, vz + D3,
      vx, vy, vz,
      mk,
      out, out + 2 * D3, out + 4 * D3,
      flag, cc);
  // Pass n=1: m=0 source is the UPDATED layer 0 (just written to out).
  dem_pass<<<grd, blk, 0, stream>>>(
      1, xg, yg, zg,
      out, out + 2 * D3, out + 4 * D3,
      vx + D3, vy + D3, vz + D3,
      vx + D3, vy + D3, vz + D3,
      mk + D3,
      out + D3, out + 3 * D3, out + 5 * D3,
      flag, cc);
}